// Round 16
// baseline (142.792 us; speedup 1.0000x reference)
//
#include <hip/hip_runtime.h>

// Chamfer loss: B=8, V=4, N=2048, D=3 fp32.
// final = per_view[0] + sum_v per_view[v]; per_view = mean_b(cham_x + cham_y)
// => weight per pair job = ((v==0)?2:1)/8 applied to cham_x+cham_y.
//
// R21 = R20's work-halving with the SYMMETRIC t-matrix (R20's col path was
// algebraically wrong: t = x.y - 0.5|y|^2 lacks the row-varying -0.5|x|^2).
// New: u = x.y - 0.5|x|^2 - 0.5|y|^2 via the two spare K-slots (k14,k15 =
// A:(sh,sl) x B:ONE, s = -0.5|x|^2 as bf16 hi/lo, mirroring w). Then
// d2 = -2u EXACTLY, and min-d2 along rows AND cols = -2 max-u: one MFMA
// pass serves both chamfer directions. 32 pairs x 8 rc x 2 col-halves =
// 512 blocks; R14's proven unroll-8 inner loop + per-pr col-max (same-j
// d-consumption, no lifetime growth) flushed via LDS u32-atomicMax
// (monotone float encoding). rowpart (min over 2 halves in combine) /
// colpart (min over 8 rc); combine + R17 ticket election (cnt initialized
// by dispatch 1 -- free) -> deterministic out[0]. Two dispatches.
//
// K-slot map (A,B share k-permutation): k0-2 xh*yh, k3-5 xh*yl, k6-8 xl*yh,
// k9-10 ONE*(wh,wl), k11-13 xl*yl, k14-15 (sh,sl)*ONE.
// C layout: col=lane&31, row=(j&3)+8*(j>>2)+4*(lane>>5).

#define B_ 8
#define V_ 4
#define N_ 2048
#define PAIRS 32
#define RPB 256                       // X rows per block
#define GRID_ 512                     // 32 pairs x 8 rc x 2 halves
#define CHUNK 512                     // cols per LDS chunk
#define NCHUNK 2                      // 1024 cols (one half) per block
#define CPITCH 24                     // ushorts per packed col (48 B)
#define CGRID 256                     // combine blocks

typedef short bf16x8 __attribute__((ext_vector_type(8)));
typedef float f32x16 __attribute__((ext_vector_type(16)));

__device__ __forceinline__ unsigned short f2bf(float f) {
  union { float f; unsigned u; } v; v.f = f;
  const unsigned r = v.u + 0x7fffu + ((v.u >> 16) & 1u);  // RNE
  return (unsigned short)(r >> 16);
}
__device__ __forceinline__ float bf2f(unsigned short h) {
  union { unsigned u; float f; } v; v.u = ((unsigned)h) << 16;
  return v.f;
}
// monotone float<->uint order-embedding (u32 atomicMax == float max)
__device__ __forceinline__ unsigned fenc(float f) {
  const unsigned u = __float_as_uint(f);
  return u ^ (0x80000000u | (unsigned)(-(int)(u >> 31)));
}
__device__ __forceinline__ float fdec(unsigned k) {
  const unsigned u = ((int)k < 0) ? (k ^ 0x80000000u) : ~k;
  return __uint_as_float(u);
}

__device__ __forceinline__ void pack_col(float y0, float y1, float y2,
                                         unsigned short* dst) {
  const unsigned short h0 = f2bf(y0), h1 = f2bf(y1), h2 = f2bf(y2);
  const unsigned short l0 = f2bf(y0 - bf2f(h0));
  const unsigned short l1 = f2bf(y1 - bf2f(h1));
  const unsigned short l2 = f2bf(y2 - bf2f(h2));
  const float w = -0.5f * fmaf(y0, y0, fmaf(y1, y1, y2 * y2));
  const unsigned short wh = f2bf(w);
  const unsigned short wl = f2bf(w - bf2f(wh));
  const unsigned short ONE = 0x3F80;  // bf16 1.0
  bf16x8 b0, b1;
  b0[0] = (short)h0; b0[1] = (short)h1; b0[2] = (short)h2;   // k0-2
  b0[3] = (short)l0; b0[4] = (short)l1; b0[5] = (short)l2;   // k3-5
  b0[6] = (short)h0; b0[7] = (short)h1;                      // k6-7
  b1[0] = (short)h2;                                         // k8
  b1[1] = (short)wh; b1[2] = (short)wl;                      // k9-10
  b1[3] = (short)l0; b1[4] = (short)l1; b1[5] = (short)l2;   // k11-13
  b1[6] = (short)ONE; b1[7] = (short)ONE;                    // k14-15 (vs sh,sl)
  *(bf16x8*)(dst) = b0;        // ds_write_b128 x2 (pitch 48, 16B-aligned)
  *(bf16x8*)(dst + 8) = b1;
}

__device__ __forceinline__ void stage_chunk(const float* __restrict__ yb,
                                            unsigned short* __restrict__ dstbuf,
                                            int halfbase, int ch, int t) {
  const int c0 = halfbase + ch * CHUNK + t * 2;
  const float2* yp2 = (const float2*)(yb + (size_t)c0 * 3);  // 8B-aligned
  const float2 u0 = yp2[0], u1 = yp2[1], u2 = yp2[2];
  unsigned short* dst = dstbuf + (size_t)(t * 2) * CPITCH;
  pack_col(u0.x, u0.y, u1.x, dst);
  pack_col(u1.y, u2.x, u2.y, dst + CPITCH);
}

__global__ __launch_bounds__(256, 2) void chamfer_main(
    const float* __restrict__ X, const float* __restrict__ T,
    float* __restrict__ rowpart, float* __restrict__ colpart,
    unsigned int* __restrict__ cnt) {
  __shared__ unsigned short yf[2][CHUNK * CPITCH];  // 2 x 24 KB
  __shared__ unsigned colp[1024];                   // encoded col u-max (4KB)

  // XCD swizzle: physical p -> XCD p&7; XCD x owns logical [x*64,(x+1)*64)
  // = 4 consecutive pairs (X,T panels L2-resident per XCD).
  const int p = blockIdx.x;
  const int bid = (p & 7) * (GRID_ / 8) + (p >> 3);
  const int pair = bid >> 4;         // [0,32)
  const int rc   = (bid >> 1) & 7;   // row-chunk of 256
  const int half = bid & 1;          // col half: cols [half*1024, +1024)
  const float* xb = X + (size_t)pair * N_ * 3;     // rows ALWAYS X
  const float* yb = T + (size_t)pair * N_ * 3;     // cols ALWAYS T
  const int t = threadIdx.x;
  const int lane = t & 63;
  const int wv = t >> 6;
  const int lr = lane & 31;          // A-row / B-col within tile
  const int g  = lane >> 5;          // K-group

  if (bid == 0 && t == 0) cnt[0] = 0;  // init election counter for dispatch 2
#pragma unroll
  for (int k = 0; k < 4; ++k) colp[t + k * 256] = 0u;  // 0 < fenc(any real)

  // ---- A fragments: this wave's 64 X-rows = 2 row-tiles of 32 ----
  bf16x8 afrag[2];
  const int rbase = rc * RPB + wv * 64;
#pragma unroll
  for (int rt = 0; rt < 2; ++rt) {
    const int r = rbase + rt * 32 + lr;
    const float x0 = xb[r * 3 + 0], x1 = xb[r * 3 + 1], x2 = xb[r * 3 + 2];
    const float s = -0.5f * fmaf(x0, x0, fmaf(x1, x1, x2 * x2));
    const unsigned short h0 = f2bf(x0), h1 = f2bf(x1), h2 = f2bf(x2);
    const unsigned short l0 = f2bf(x0 - bf2f(h0));
    const unsigned short l1 = f2bf(x1 - bf2f(h1));
    const unsigned short l2 = f2bf(x2 - bf2f(h2));
    const unsigned short sh = f2bf(s);
    const unsigned short sl = f2bf(s - bf2f(sh));
    const unsigned short ONE = 0x3F80;  // bf16 1.0
    bf16x8 a;
    if (g == 0) {  // k0-7
      a[0] = (short)h0; a[1] = (short)h1; a[2] = (short)h2;
      a[3] = (short)h0; a[4] = (short)h1; a[5] = (short)h2;
      a[6] = (short)l0; a[7] = (short)l1;
    } else {       // k8-15
      a[0] = (short)l2; a[1] = (short)ONE; a[2] = (short)ONE;
      a[3] = (short)l0; a[4] = (short)l1; a[5] = (short)l2;
      a[6] = (short)sh; a[7] = (short)sl;
    }
    afrag[rt] = a;
  }

  f32x16 r0, r1;
#pragma unroll
  for (int j = 0; j < 16; ++j) { r0[j] = -1e30f; r1[j] = -1e30f; }

  stage_chunk(yb, yf[0], half * 1024, 0, t);
  __syncthreads();

  for (int ch = 0; ch < NCHUNK; ++ch) {
    if (ch + 1 < NCHUNK)                       // inline staging (R14-proven)
      stage_chunk(yb, yf[1], half * 1024, 1, t);
    const unsigned short* yfb = yf[ch & 1];
#pragma unroll
    for (int pr = 0; pr < CHUNK / 64; ++pr) {  // 8 col-tile pairs
      const unsigned short* pa = yfb + (size_t)(pr * 64 + lr) * CPITCH + g * 8;
      const bf16x8 bA = *(const bf16x8*)pa;                    // ds_read_b128
      const bf16x8 bB = *(const bf16x8*)(pa + 32 * CPITCH);
      const f32x16 d00 =
          __builtin_amdgcn_mfma_f32_32x32x16_bf16(afrag[0], bA, (f32x16){}, 0, 0, 0);
      const f32x16 d10 =
          __builtin_amdgcn_mfma_f32_32x32x16_bf16(afrag[1], bA, (f32x16){}, 0, 0, 0);
      const f32x16 d01 =
          __builtin_amdgcn_mfma_f32_32x32x16_bf16(afrag[0], bB, (f32x16){}, 0, 0, 0);
      const f32x16 d11 =
          __builtin_amdgcn_mfma_f32_32x32x16_bf16(afrag[1], bB, (f32x16){}, 0, 0, 0);
      float cmA = -1e30f, cmB = -1e30f;        // col-max accumulators
#pragma unroll
      for (int j = 0; j < 16; ++j) {           // each d: 2 same-j consumers
        r0[j] = fmaxf(fmaxf(r0[j], d00[j]), d01[j]);
        r1[j] = fmaxf(fmaxf(r1[j], d10[j]), d11[j]);
        cmA = fmaxf(fmaxf(cmA, d00[j]), d10[j]);   // col lr of tile A
        cmB = fmaxf(fmaxf(cmB, d01[j]), d11[j]);   // col lr of tile B
      }
      cmA = fmaxf(cmA, __shfl_xor(cmA, 32, 64));   // merge g-halves (rows)
      cmB = fmaxf(cmB, __shfl_xor(cmB, 32, 64));
      if (lane < 32) {                             // flush to LDS col-max
        atomicMax(&colp[ch * CHUNK + pr * 64 + lr], fenc(cmA));
        atomicMax(&colp[ch * CHUNK + pr * 64 + 32 + lr], fenc(cmB));
      }
    }
    __syncthreads();  // staging visible; reads+flushes of ch done
  }

  // ---- col tail: colp complete; d2 = -2*umax ----
#pragma unroll
  for (int k = 0; k < 4; ++k) {
    const int c = t + k * 256;
    colpart[(size_t)bid * 1024 + c] = -2.0f * fdec(colp[c]);
  }

  // ---- row tail (R14 pane, yf dead): [64][33] f32/wave, bank (row+col)%32
  float* tw = ((float*)&yf[0][0]) + wv * (64 * 33);
#pragma unroll
  for (int rt = 0; rt < 2; ++rt) {
#pragma unroll
    for (int j = 0; j < 16; ++j) {
      const int rl = rt * 32 + (j & 3) + 8 * (j >> 2) + 4 * g;
      tw[rl * 33 + lr] = rt ? r1[j] : r0[j];
    }
  }
  __syncthreads();
  float mx = -1e30f;
#pragma unroll
  for (int c = 0; c < 32; ++c) mx = fmaxf(mx, tw[lane * 33 + c]);
  // rowpart: partial d2 over this col-half; combine takes min of 2 halves
  rowpart[(size_t)bid * 256 + t] = -2.0f * mx;
}

__global__ __launch_bounds__(256) void chamfer_combine(
    const float* __restrict__ rowpart, const float* __restrict__ colpart,
    float* __restrict__ cpart, unsigned int* __restrict__ cnt,
    float* __restrict__ out) {
  __shared__ float red4[4];
  __shared__ int lastflag;
  const int t = threadIdx.x;
  const int blk = blockIdx.x;
  const int tid = blk * 256 + t;                 // [0, 65536)
  const int pair = tid >> 11;
  const int idx = tid & 2047;
  // cham_x item (pair, row=idx): min over 2 col-halves
  const int rcx = idx >> 8, rr = idx & 255;
  const int b0 = pair * 16 + rcx * 2;
  const float dx = fminf(rowpart[(size_t)b0 * 256 + rr],
                         rowpart[(size_t)(b0 + 1) * 256 + rr]);
  // cham_y item (pair, col=idx): min over 8 row-chunks
  const int halfc = idx >> 10, cc = idx & 1023;
  float dy = 1e30f;
#pragma unroll
  for (int r8 = 0; r8 < 8; ++r8)
    dy = fminf(dy, colpart[(size_t)(pair * 16 + r8 * 2 + halfc) * 1024 + cc]);
  const float w = (((pair & (V_ - 1)) == 0) ? 2.0f : 1.0f) * (1.0f / (float)B_);
  float s = w * (dx + dy);
#pragma unroll
  for (int o = 32; o > 0; o >>= 1) s += __shfl_down(s, o, 64);
  const int lane = t & 63, wv = t >> 6;
  if (lane == 0) red4[wv] = s;
  __syncthreads();
  if (t == 0) {
    cpart[blk] = (red4[0] + red4[1]) + (red4[2] + red4[3]);  // plain store
    const unsigned ticket = __hip_atomic_fetch_add(
        cnt, 1u, __ATOMIC_ACQ_REL, __HIP_MEMORY_SCOPE_AGENT);
    lastflag = (ticket == CGRID - 1) ? 1 : 0;   // cnt=0 init by dispatch 1
  }
  __syncthreads();
  if (lastflag) {                                // true last block: finish
    float v = cpart[t];
#pragma unroll
    for (int o = 32; o > 0; o >>= 1) v += __shfl_down(v, o, 64);
    if (lane == 0) red4[wv] = v;
    __syncthreads();
    if (t == 0) out[0] = (red4[0] + red4[1]) + (red4[2] + red4[3]);
  }
}

extern "C" void kernel_launch(void* const* d_in, const int* in_sizes, int n_in,
                              void* d_out, int out_size, void* d_ws, size_t ws_size,
                              hipStream_t stream) {
  const float* X = (const float*)d_in[0];
  const float* T = (const float*)d_in[1];
  float* out = (float*)d_out;
  unsigned int* cnt = (unsigned int*)d_ws;                  // 16B slot
  float* rowpart = (float*)((char*)d_ws + 16);              // 512*256 = 512KB
  float* colpart = rowpart + (size_t)GRID_ * 256;           // 512*1024 = 2MB
  float* cpart = colpart + (size_t)GRID_ * 1024;            // 256 floats

  chamfer_main<<<GRID_, 256, 0, stream>>>(X, T, rowpart, colpart, cnt);
  chamfer_combine<<<CGRID, 256, 0, stream>>>(rowpart, colpart, cpart, cnt, out);
}

// Round 17
// 24.524 us; speedup vs baseline: 5.8225x; 5.8225x over previous
//
#include <hip/hip_runtime.h>

// Chamfer loss: B=8, V=4, N=2048, D=3 fp32.
// final = per_view[0] + sum_v per_view[v]; per_view = mean_b(cham_x + cham_y)
// => weight per pair job = ((v==0)?2:1)/8 applied to cham_x+cham_y.
//
// R22 = R21 (symmetric work-halving, math verified absmax 0.0) with R19's
// fence-disciplined inner loop (R21's unroll-8 + col-max kept all 4 d-tiles
// live through the j-loop -> AGPR spill, 400MB scratch, 142us).
// u = x.y - 0.5|x|^2 - 0.5|y|^2 in ONE MFMA (spare k14-15 = (sh,sl)*ONE);
// d2 = -2u, so min-d2 over rows AND cols from one pass. 32 pairs x 8 rc x
// 2 col-halves = 512 blocks at (256,2). Inner loop: unroll 1 + 1-deep
// B-frag prefetch + sched_barrier(0) mid-body (R19-proven no-spill): d00/d01
// die into r0+cm before d10/d11 exist -> <=2 d-tiles live, ~130 regs total.
// Col-maxes flushed per-iter via LDS u32-atomicMax (monotone float enc,
// lanes->distinct banks). rowpart (min2 in combine) / colpart (min8);
// combine + R17 ticket election (cnt init'd by dispatch 1) -> out[0].
//
// K-slot map (A,B share k-permutation): k0-2 xh*yh, k3-5 xh*yl, k6-8 xl*yh,
// k9-10 ONE*(wh,wl), k11-13 xl*yl, k14-15 (sh,sl)*ONE.
// C layout: col=lane&31, row=(j&3)+8*(j>>2)+4*(lane>>5).

#define B_ 8
#define V_ 4
#define N_ 2048
#define PAIRS 32
#define RPB 256                       // X rows per block
#define GRID_ 512                     // 32 pairs x 8 rc x 2 halves
#define CHUNK 512                     // cols per LDS chunk
#define NCHUNK 2                      // 1024 cols (one half) per block
#define CPITCH 24                     // ushorts per packed col (48 B)
#define CGRID 256                     // combine blocks

typedef short bf16x8 __attribute__((ext_vector_type(8)));
typedef float f32x16 __attribute__((ext_vector_type(16)));

__device__ __forceinline__ unsigned short f2bf(float f) {
  union { float f; unsigned u; } v; v.f = f;
  const unsigned r = v.u + 0x7fffu + ((v.u >> 16) & 1u);  // RNE
  return (unsigned short)(r >> 16);
}
__device__ __forceinline__ float bf2f(unsigned short h) {
  union { unsigned u; float f; } v; v.u = ((unsigned)h) << 16;
  return v.f;
}
// monotone float<->uint order-embedding (u32 atomicMax == float max)
__device__ __forceinline__ unsigned fenc(float f) {
  const unsigned u = __float_as_uint(f);
  return u ^ (0x80000000u | (unsigned)(-(int)(u >> 31)));
}
__device__ __forceinline__ float fdec(unsigned k) {
  const unsigned u = ((int)k < 0) ? (k ^ 0x80000000u) : ~k;
  return __uint_as_float(u);
}

__device__ __forceinline__ void pack_col(float y0, float y1, float y2,
                                         unsigned short* dst) {
  const unsigned short h0 = f2bf(y0), h1 = f2bf(y1), h2 = f2bf(y2);
  const unsigned short l0 = f2bf(y0 - bf2f(h0));
  const unsigned short l1 = f2bf(y1 - bf2f(h1));
  const unsigned short l2 = f2bf(y2 - bf2f(h2));
  const float w = -0.5f * fmaf(y0, y0, fmaf(y1, y1, y2 * y2));
  const unsigned short wh = f2bf(w);
  const unsigned short wl = f2bf(w - bf2f(wh));
  const unsigned short ONE = 0x3F80;  // bf16 1.0
  bf16x8 b0, b1;
  b0[0] = (short)h0; b0[1] = (short)h1; b0[2] = (short)h2;   // k0-2
  b0[3] = (short)l0; b0[4] = (short)l1; b0[5] = (short)l2;   // k3-5
  b0[6] = (short)h0; b0[7] = (short)h1;                      // k6-7
  b1[0] = (short)h2;                                         // k8
  b1[1] = (short)wh; b1[2] = (short)wl;                      // k9-10
  b1[3] = (short)l0; b1[4] = (short)l1; b1[5] = (short)l2;   // k11-13
  b1[6] = (short)ONE; b1[7] = (short)ONE;                    // k14-15 (vs sh,sl)
  *(bf16x8*)(dst) = b0;        // ds_write_b128 x2 (pitch 48, 16B-aligned)
  *(bf16x8*)(dst + 8) = b1;
}

__device__ __forceinline__ void stage_chunk(const float* __restrict__ yb,
                                            unsigned short* __restrict__ dstbuf,
                                            int halfbase, int ch, int t) {
  const int c0 = halfbase + ch * CHUNK + t * 2;
  const float2* yp2 = (const float2*)(yb + (size_t)c0 * 3);  // 8B-aligned
  const float2 u0 = yp2[0], u1 = yp2[1], u2 = yp2[2];
  unsigned short* dst = dstbuf + (size_t)(t * 2) * CPITCH;
  pack_col(u0.x, u0.y, u1.x, dst);
  pack_col(u1.y, u2.x, u2.y, dst + CPITCH);
}

__global__ __launch_bounds__(256, 2) void chamfer_main(
    const float* __restrict__ X, const float* __restrict__ T,
    float* __restrict__ rowpart, float* __restrict__ colpart,
    unsigned int* __restrict__ cnt) {
  __shared__ unsigned short yf[2][CHUNK * CPITCH];  // 2 x 24 KB
  __shared__ unsigned colp[1024];                   // encoded col u-max (4KB)

  // XCD swizzle: physical p -> XCD p&7; XCD x owns logical [x*64,(x+1)*64)
  // = 4 consecutive pairs (X,T panels L2-resident per XCD).
  const int p = blockIdx.x;
  const int bid = (p & 7) * (GRID_ / 8) + (p >> 3);
  const int pair = bid >> 4;         // [0,32)
  const int rc   = (bid >> 1) & 7;   // row-chunk of 256
  const int half = bid & 1;          // col half: cols [half*1024, +1024)
  const float* xb = X + (size_t)pair * N_ * 3;     // rows ALWAYS X
  const float* yb = T + (size_t)pair * N_ * 3;     // cols ALWAYS T
  const int t = threadIdx.x;
  const int lane = t & 63;
  const int wv = t >> 6;
  const int lr = lane & 31;          // A-row / B-col within tile
  const int g  = lane >> 5;          // K-group

  if (bid == 0 && t == 0) cnt[0] = 0;  // init election counter for dispatch 2
#pragma unroll
  for (int k = 0; k < 4; ++k) colp[t + k * 256] = 0u;  // 0 < fenc(any real)

  // ---- A fragments: this wave's 64 X-rows = 2 row-tiles of 32 ----
  bf16x8 afrag[2];
  const int rbase = rc * RPB + wv * 64;
#pragma unroll
  for (int rt = 0; rt < 2; ++rt) {
    const int r = rbase + rt * 32 + lr;
    const float x0 = xb[r * 3 + 0], x1 = xb[r * 3 + 1], x2 = xb[r * 3 + 2];
    const float s = -0.5f * fmaf(x0, x0, fmaf(x1, x1, x2 * x2));
    const unsigned short h0 = f2bf(x0), h1 = f2bf(x1), h2 = f2bf(x2);
    const unsigned short l0 = f2bf(x0 - bf2f(h0));
    const unsigned short l1 = f2bf(x1 - bf2f(h1));
    const unsigned short l2 = f2bf(x2 - bf2f(h2));
    const unsigned short sh = f2bf(s);
    const unsigned short sl = f2bf(s - bf2f(sh));
    const unsigned short ONE = 0x3F80;  // bf16 1.0
    bf16x8 a;
    if (g == 0) {  // k0-7
      a[0] = (short)h0; a[1] = (short)h1; a[2] = (short)h2;
      a[3] = (short)h0; a[4] = (short)h1; a[5] = (short)h2;
      a[6] = (short)l0; a[7] = (short)l1;
    } else {       // k8-15
      a[0] = (short)l2; a[1] = (short)ONE; a[2] = (short)ONE;
      a[3] = (short)l0; a[4] = (short)l1; a[5] = (short)l2;
      a[6] = (short)sh; a[7] = (short)sl;
    }
    afrag[rt] = a;
  }

  f32x16 r0, r1;
#pragma unroll
  for (int j = 0; j < 16; ++j) { r0[j] = -1e30f; r1[j] = -1e30f; }

  stage_chunk(yb, yf[0], half * 1024, 0, t);
  __syncthreads();

  for (int ch = 0; ch < NCHUNK; ++ch) {
    if (ch + 1 < NCHUNK)                       // inline staging (R14-proven)
      stage_chunk(yb, yf[1], half * 1024, 1, t);
    const unsigned short* yfb = yf[ch & 1];
    const unsigned short* pa0 = yfb + (size_t)lr * CPITCH + g * 8;
    // R19-proven fence-disciplined loop: unroll 1 + 1-deep prefetch;
    // sched_barrier(0) kills d00/d01 before d10/d11 exist (<=2 d-tiles live).
    bf16x8 cA = *(const bf16x8*)pa0;
    bf16x8 cB = *(const bf16x8*)(pa0 + 32 * CPITCH);
#pragma unroll 1
    for (int pr = 0; pr < CHUNK / 64; ++pr) {  // 8 col-tile pairs
      const int nx = (pr + 1) & 7;             // wraps on last iter (harmless)
      const bf16x8 nA = *(const bf16x8*)(pa0 + (size_t)(nx * 64) * CPITCH);
      const bf16x8 nB = *(const bf16x8*)(pa0 + (size_t)(nx * 64 + 32) * CPITCH);
      float cmA = -1e30f, cmB = -1e30f;        // col-max for this tile pair
      const f32x16 d00 =
          __builtin_amdgcn_mfma_f32_32x32x16_bf16(afrag[0], cA, (f32x16){}, 0, 0, 0);
      const f32x16 d01 =
          __builtin_amdgcn_mfma_f32_32x32x16_bf16(afrag[0], cB, (f32x16){}, 0, 0, 0);
#pragma unroll
      for (int j = 0; j < 16; ++j) {
        r0[j] = fmaxf(fmaxf(r0[j], d00[j]), d01[j]);
        cmA = fmaxf(cmA, d00[j]);
        cmB = fmaxf(cmB, d01[j]);
      }
      __builtin_amdgcn_sched_barrier(0);       // d00/d01 dead before d10/d11
      const f32x16 d10 =
          __builtin_amdgcn_mfma_f32_32x32x16_bf16(afrag[1], cA, (f32x16){}, 0, 0, 0);
      const f32x16 d11 =
          __builtin_amdgcn_mfma_f32_32x32x16_bf16(afrag[1], cB, (f32x16){}, 0, 0, 0);
#pragma unroll
      for (int j = 0; j < 16; ++j) {
        r1[j] = fmaxf(fmaxf(r1[j], d10[j]), d11[j]);
        cmA = fmaxf(cmA, d10[j]);
        cmB = fmaxf(cmB, d11[j]);
      }
      cmA = fmaxf(cmA, __shfl_xor(cmA, 32, 64));   // merge g-halves (rows)
      cmB = fmaxf(cmB, __shfl_xor(cmB, 32, 64));
      if (lane < 32) {                             // flush: distinct banks
        atomicMax(&colp[ch * CHUNK + pr * 64 + lr], fenc(cmA));
        atomicMax(&colp[ch * CHUNK + pr * 64 + 32 + lr], fenc(cmB));
      }
      cA = nA;
      cB = nB;
    }
    __syncthreads();  // staging visible; reads+flushes of ch done
  }

  // ---- col tail: colp complete; d2 = -2*umax ----
#pragma unroll
  for (int k = 0; k < 4; ++k) {
    const int c = t + k * 256;
    colpart[(size_t)bid * 1024 + c] = -2.0f * fdec(colp[c]);
  }

  // ---- row tail (R14 pane, yf dead): [64][33] f32/wave, bank (row+col)%32
  float* tw = ((float*)&yf[0][0]) + wv * (64 * 33);
#pragma unroll
  for (int rt = 0; rt < 2; ++rt) {
#pragma unroll
    for (int j = 0; j < 16; ++j) {
      const int rl = rt * 32 + (j & 3) + 8 * (j >> 2) + 4 * g;
      tw[rl * 33 + lr] = rt ? r1[j] : r0[j];
    }
  }
  __syncthreads();
  float mx = -1e30f;
#pragma unroll
  for (int c = 0; c < 32; ++c) mx = fmaxf(mx, tw[lane * 33 + c]);
  // rowpart: partial d2 over this col-half; combine takes min of 2 halves
  rowpart[(size_t)bid * 256 + t] = -2.0f * mx;
}

__global__ __launch_bounds__(256) void chamfer_combine(
    const float* __restrict__ rowpart, const float* __restrict__ colpart,
    float* __restrict__ cpart, unsigned int* __restrict__ cnt,
    float* __restrict__ out) {
  __shared__ float red4[4];
  __shared__ int lastflag;
  const int t = threadIdx.x;
  const int blk = blockIdx.x;
  const int tid = blk * 256 + t;                 // [0, 65536)
  const int pair = tid >> 11;
  const int idx = tid & 2047;
  // cham_x item (pair, row=idx): min over 2 col-halves
  const int rcx = idx >> 8, rr = idx & 255;
  const int b0 = pair * 16 + rcx * 2;
  const float dx = fminf(rowpart[(size_t)b0 * 256 + rr],
                         rowpart[(size_t)(b0 + 1) * 256 + rr]);
  // cham_y item (pair, col=idx): min over 8 row-chunks
  const int halfc = idx >> 10, cc = idx & 1023;
  float dy = 1e30f;
#pragma unroll
  for (int r8 = 0; r8 < 8; ++r8)
    dy = fminf(dy, colpart[(size_t)(pair * 16 + r8 * 2 + halfc) * 1024 + cc]);
  const float w = (((pair & (V_ - 1)) == 0) ? 2.0f : 1.0f) * (1.0f / (float)B_);
  float s = w * (dx + dy);
#pragma unroll
  for (int o = 32; o > 0; o >>= 1) s += __shfl_down(s, o, 64);
  const int lane = t & 63, wv = t >> 6;
  if (lane == 0) red4[wv] = s;
  __syncthreads();
  if (t == 0) {
    cpart[blk] = (red4[0] + red4[1]) + (red4[2] + red4[3]);  // plain store
    const unsigned ticket = __hip_atomic_fetch_add(
        cnt, 1u, __ATOMIC_ACQ_REL, __HIP_MEMORY_SCOPE_AGENT);
    lastflag = (ticket == CGRID - 1) ? 1 : 0;   // cnt=0 init by dispatch 1
  }
  __syncthreads();
  if (lastflag) {                                // true last block: finish
    float v = cpart[t];
#pragma unroll
    for (int o = 32; o > 0; o >>= 1) v += __shfl_down(v, o, 64);
    if (lane == 0) red4[wv] = v;
    __syncthreads();
    if (t == 0) out[0] = (red4[0] + red4[1]) + (red4[2] + red4[3]);
  }
}

extern "C" void kernel_launch(void* const* d_in, const int* in_sizes, int n_in,
                              void* d_out, int out_size, void* d_ws, size_t ws_size,
                              hipStream_t stream) {
  const float* X = (const float*)d_in[0];
  const float* T = (const float*)d_in[1];
  float* out = (float*)d_out;
  unsigned int* cnt = (unsigned int*)d_ws;                  // 16B slot
  float* rowpart = (float*)((char*)d_ws + 16);              // 512*256 = 512KB
  float* colpart = rowpart + (size_t)GRID_ * 256;           // 512*1024 = 2MB
  float* cpart = colpart + (size_t)GRID_ * 1024;            // 256 floats

  chamfer_main<<<GRID_, 256, 0, stream>>>(X, T, rowpart, colpart, cnt);
  chamfer_combine<<<CGRID, 256, 0, stream>>>(rowpart, colpart, cpart, cnt, out);
}